// Round 13
// baseline (18.911 us; speedup 1.0000x reference)
//
#include <hip/hip_runtime.h>

// Problem constants (fixed by the bench: B=8, L=512, T=4096, D=512).
constexpr int B = 8;
constexpr int L = 512;
constexpr int D = 512;
constexpr int T = 4096;

constexpr int OUT_REP = B * D * T;        // offset of repeats in d_out
constexpr int OUT_LAT = OUT_REP + B * L;  // offset of latent_lengths

// clang native vector type: __builtin_nontemporal_* requires real vector
// types, not HIP_vector_type structs.
typedef float f32x4 __attribute__((ext_vector_type(4)));

// R13 = R12 with the nontemporal builtins on native ext_vector_type.
// Theory unchanged: write-allocate of the never-re-read 67 MB stream through
// the 32 MB L2 is the last path difference vs fillBufferAligned's 6.4 TB/s.
__global__ __launch_bounds__(256) void encoder_expand_kernel(
    const float* __restrict__ enc,   // (B, D, L)
    const float* __restrict__ dur,   // (B, L)
    float* __restrict__ out)         // [expanded (B,D,T) | repeats (B,L) | latent (B)]
{
    const int bid = blockIdx.x;
    const int b   = bid >> 8;               // 0..7
    const int rp  = bid & 255;              // row pair 0..255 (d = 2*rp, 2*rp+1)
    const int tid = threadIdx.x;
    const int lane = tid & 63;
    const int wave = tid >> 6;              // 0..3

    __shared__ unsigned short lut[T];       // 8 KB  t -> l, 0xFFFF = past end
    __shared__ float rows[2 * L];           // 4 KB  staged enc rows
    __shared__ int wave_tot[4];

    // ---- issue global loads first (independent) ----
    const float2 dur2 = *reinterpret_cast<const float2*>(dur + b * L + 2 * tid);
    const float* encp = enc + ((size_t)b * D + 2 * rp) * L;   // 2 rows, contiguous
    const f32x4 rv = __builtin_nontemporal_load(
        reinterpret_cast<const f32x4*>(encp) + tid);           // 4 KB coalesced, nt

    // ---- init LUT sentinel (2048 u32) while loads are in flight ----
    #pragma unroll
    for (int i = 0; i < T / 2 / 256; ++i)
        reinterpret_cast<unsigned*>(lut)[i * 256 + tid] = 0xFFFFFFFFu;

    // ---- stage enc rows ----
    reinterpret_cast<f32x4*>(rows)[tid] = rv;

    // ---- repeats + scan over L=512 (2 elems/thread) ----
    const int r0 = (int)floorf(dur2.x + 0.5f);
    const int r1 = (int)floorf(dur2.y + 0.5f);
    const int pair = r0 + r1;

    int scan = pair;                        // wave-level inclusive scan
    #pragma unroll
    for (int off = 1; off < 64; off <<= 1) {
        int n = __shfl_up(scan, off, 64);
        if (lane >= off) scan += n;
    }
    if (lane == 63) wave_tot[wave] = scan;
    __syncthreads();                        // lut init + rows + wave_tot visible

    int wpre = 0;
    #pragma unroll
    for (int w = 0; w < 4; ++w) wpre += (w < wave) ? wave_tot[w] : 0;
    int k = wpre + scan - pair;             // exclusive prefix = t-start of l0's span
    const int total = wave_tot[0] + wave_tot[1] + wave_tot[2] + wave_tot[3];

    // ---- scatter: each l writes its own span (disjoint ranges, no race) ----
    const int l0 = 2 * tid;
    for (int q = 0; q < r0; ++q, ++k) if (k < T) lut[k] = (unsigned short)l0;
    for (int q = 0; q < r1; ++q, ++k) if (k < T) lut[k] = (unsigned short)(l0 + 1);

    // ---- side outputs (one block per batch) ----
    if (rp == 0) {
        out[OUT_REP + b * L + l0]     = (float)r0;
        out[OUT_REP + b * L + l0 + 1] = (float)r1;
        if (tid == 0) out[OUT_LAT + b] = (float)total;
    }
    __syncthreads();                        // scatter done

    // ---- payload: 8 sequential block-wide 4 KB sweeps over the 32 KB span ----
    f32x4* out4 = reinterpret_cast<f32x4*>(out + ((size_t)b * D + 2 * rp) * T);

    #pragma unroll
    for (int s = 0; s < 8; ++s) {
        const int row = s >> 2;             // 0..1
        const int seg = s & 3;              // 0..3 (1024-t segment)
        const int t0  = seg * 1024 + 4 * tid;

        f32x4 v = (f32x4)(0.0f);
        if (seg * 1024 < total) {           // block-uniform zero-skip
            const uint2 lu = *reinterpret_cast<const uint2*>(&lut[t0]);
            const int la = lu.x & 0xffff, lb = lu.x >> 16;
            const int lc = lu.y & 0xffff, ld = lu.y >> 16;
            const float* rowp = rows + row * L;
            v.x = rowp[la & 511];           // monotone l across lanes: ~2-way banks (free)
            v.y = rowp[lb & 511];
            v.z = rowp[lc & 511];
            v.w = rowp[ld & 511];
            if (la == 0xffff) v.x = 0.0f;
            if (lb == 0xffff) v.y = 0.0f;
            if (lc == 0xffff) v.z = 0.0f;
            if (ld == 0xffff) v.w = 0.0f;
        }
        // nontemporal: bypass L2/L3 allocation for the never-re-read stream
        __builtin_nontemporal_store(v, out4 + (row * 4 + seg) * 256 + tid);
    }
}

extern "C" void kernel_launch(void* const* d_in, const int* in_sizes, int n_in,
                              void* d_out, int out_size, void* d_ws, size_t ws_size,
                              hipStream_t stream) {
    const float* enc = (const float*)d_in[0];   // (B, D, L) fp32
    const float* dur = (const float*)d_in[1];   // (B, L)    fp32
    float* out = (float*)d_out;
    encoder_expand_kernel<<<dim3(B * (D / 2)), dim3(256), 0, stream>>>(enc, dur, out);
}

// Round 14
// 18.001 us; speedup vs baseline: 1.0505x; 1.0505x over previous
//
#include <hip/hip_runtime.h>

// Problem constants (fixed by the bench: B=8, L=512, T=4096, D=512).
constexpr int B = 8;
constexpr int L = 512;
constexpr int D = 512;
constexpr int T = 4096;
constexpr int ROWS = 4;                   // d-rows per block (contiguous span)
constexpr int NSWEEP = ROWS * 4;          // 4 KB sweeps per block

constexpr int OUT_REP = B * D * T;        // offset of repeats in d_out
constexpr int OUT_LAT = OUT_REP + B * L;  // offset of latent_lengths

// R14 = R10 (plain stores — R13 showed nt hurts; linear bid — R11 showed
// swizzle neutral) with ROWS 2 -> 4: each block owns one contiguous 64 KB
// output span (1024 blocks, 4/CU, single occupancy round). Tests whether
// per-stream DRAM grain (32 KB -> 64 KB, 2048 -> 1024 concurrent streams)
// is the residual limiter.
__global__ __launch_bounds__(256) void encoder_expand_kernel(
    const float* __restrict__ enc,   // (B, D, L)
    const float* __restrict__ dur,   // (B, L)
    float* __restrict__ out)         // [expanded (B,D,T) | repeats (B,L) | latent (B)]
{
    const int bid = blockIdx.x;
    const int b   = bid >> 7;               // 0..7
    const int rp  = bid & 127;              // row group (d = ROWS*rp ..)
    const int tid = threadIdx.x;
    const int lane = tid & 63;
    const int wave = tid >> 6;              // 0..3

    __shared__ unsigned short lut[T];       // 8 KB  t -> l, 0xFFFF = past end
    __shared__ float rows[ROWS * L];        // 8 KB  staged enc rows
    __shared__ int wave_tot[4];

    // ---- issue global loads first (independent) ----
    const float2 dur2 = *reinterpret_cast<const float2*>(dur + b * L + 2 * tid);
    const float* encp = enc + ((size_t)b * D + ROWS * rp) * L;  // ROWS rows, contiguous
    const float4 rv0 = reinterpret_cast<const float4*>(encp)[tid];
    const float4 rv1 = reinterpret_cast<const float4*>(encp)[tid + 256];

    // ---- init LUT sentinel (2048 u32) while loads are in flight ----
    #pragma unroll
    for (int i = 0; i < T / 2 / 256; ++i)
        reinterpret_cast<unsigned*>(lut)[i * 256 + tid] = 0xFFFFFFFFu;

    // ---- stage enc rows ----
    reinterpret_cast<float4*>(rows)[tid]       = rv0;
    reinterpret_cast<float4*>(rows)[tid + 256] = rv1;

    // ---- repeats + scan over L=512 (2 elems/thread) ----
    const int r0 = (int)floorf(dur2.x + 0.5f);
    const int r1 = (int)floorf(dur2.y + 0.5f);
    const int pair = r0 + r1;

    int scan = pair;                        // wave-level inclusive scan
    #pragma unroll
    for (int off = 1; off < 64; off <<= 1) {
        int n = __shfl_up(scan, off, 64);
        if (lane >= off) scan += n;
    }
    if (lane == 63) wave_tot[wave] = scan;
    __syncthreads();                        // lut init + rows + wave_tot visible

    int wpre = 0;
    #pragma unroll
    for (int w = 0; w < 4; ++w) wpre += (w < wave) ? wave_tot[w] : 0;
    int k = wpre + scan - pair;             // exclusive prefix = t-start of l0's span
    const int total = wave_tot[0] + wave_tot[1] + wave_tot[2] + wave_tot[3];

    // ---- scatter: each l writes its own span (disjoint ranges, no race) ----
    const int l0 = 2 * tid;
    for (int q = 0; q < r0; ++q, ++k) if (k < T) lut[k] = (unsigned short)l0;
    for (int q = 0; q < r1; ++q, ++k) if (k < T) lut[k] = (unsigned short)(l0 + 1);

    // ---- side outputs (one block per batch) ----
    if (rp == 0) {
        out[OUT_REP + b * L + l0]     = (float)r0;
        out[OUT_REP + b * L + l0 + 1] = (float)r1;
        if (tid == 0) out[OUT_LAT + b] = (float)total;
    }
    __syncthreads();                        // scatter done

    // ---- payload: NSWEEP sequential block-wide 4 KB sweeps over the span ----
    float4* out4 = reinterpret_cast<float4*>(out + ((size_t)b * D + ROWS * rp) * T);

    #pragma unroll
    for (int s = 0; s < NSWEEP; ++s) {
        const int row = s >> 2;             // 0..ROWS-1
        const int seg = s & 3;              // 0..3 (1024-t segment)
        const int t0  = seg * 1024 + 4 * tid;

        float4 v = make_float4(0.f, 0.f, 0.f, 0.f);
        if (seg * 1024 < total) {           // block-uniform zero-skip
            const uint2 lu = *reinterpret_cast<const uint2*>(&lut[t0]);
            const int la = lu.x & 0xffff, lb = lu.x >> 16;
            const int lc = lu.y & 0xffff, ld = lu.y >> 16;
            const float* rowp = rows + row * L;
            v.x = rowp[la & 511];           // monotone l across lanes: ~2-way banks (free)
            v.y = rowp[lb & 511];
            v.z = rowp[lc & 511];
            v.w = rowp[ld & 511];
            if (la == 0xffff) v.x = 0.0f;
            if (lb == 0xffff) v.y = 0.0f;
            if (lc == 0xffff) v.z = 0.0f;
            if (ld == 0xffff) v.w = 0.0f;
        }
        out4[s * 256 + tid] = v;            // block-wide 4 KB sequential store
    }
}

extern "C" void kernel_launch(void* const* d_in, const int* in_sizes, int n_in,
                              void* d_out, int out_size, void* d_ws, size_t ws_size,
                              hipStream_t stream) {
    const float* enc = (const float*)d_in[0];   // (B, D, L) fp32
    const float* dur = (const float*)d_in[1];   // (B, L)    fp32
    float* out = (float*)d_out;
    encoder_expand_kernel<<<dim3(B * (D / ROWS)), dim3(256), 0, stream>>>(enc, dur, out);
}

// Round 15
// 16.908 us; speedup vs baseline: 1.1184x; 1.0646x over previous
//
#include <hip/hip_runtime.h>

// Problem constants (fixed by the bench: B=8, L=512, T=4096, D=512).
constexpr int B = 8;
constexpr int L = 512;
constexpr int D = 512;
constexpr int T = 4096;
constexpr int ROWS = 4;                   // d-rows per block (contiguous 64 KB span)

constexpr int OUT_REP = B * D * T;        // offset of repeats in d_out
constexpr int OUT_LAT = OUT_REP + B * L;  // offset of latent_lengths

// R15: 512-thread blocks, ROWS=4 -> 1024 blocks x 8 waves = 4 blocks/CU,
// 32 waves/CU (FULL occupancy, unlike R14's 16) with 64 KB contiguous span
// per block. All 4 rows share identical gather indices per t-half, so the
// LUT is read ONCE per half (2 ds_read_b64/thread instead of 8) and the
// scan preamble handles 1 dur element/thread.
__global__ __launch_bounds__(512, 8) void encoder_expand_kernel(
    const float* __restrict__ enc,   // (B, D, L)
    const float* __restrict__ dur,   // (B, L)
    float* __restrict__ out)         // [expanded (B,D,T) | repeats (B,L) | latent (B)]
{
    const int bid = blockIdx.x;
    const int b   = bid >> 7;               // 0..7
    const int rp  = bid & 127;              // row group (d = 4*rp .. 4*rp+3)
    const int tid = threadIdx.x;            // 0..511
    const int lane = tid & 63;
    const int wave = tid >> 6;              // 0..7

    __shared__ unsigned short lut[T];       // 8 KB  t -> l, 0xFFFF = past end
    __shared__ float rows[ROWS * L];        // 8 KB  staged enc rows
    __shared__ int wave_tot[8];

    // ---- issue global loads first (independent) ----
    const float dv = dur[b * L + tid];      // 2 KB coalesced (tid spans L)
    const float* encp = enc + ((size_t)b * D + ROWS * rp) * L;  // 4 rows, contiguous
    const float4 rv = reinterpret_cast<const float4*>(encp)[tid];  // 8 KB coalesced

    // ---- init LUT sentinel (512 x 16 B) while loads are in flight ----
    reinterpret_cast<int4*>(lut)[tid] = make_int4(-1, -1, -1, -1);

    // ---- stage enc rows ----
    reinterpret_cast<float4*>(rows)[tid] = rv;

    // ---- repeats + scan over L=512 (1 elem/thread) ----
    const int r = (int)floorf(dv + 0.5f);

    int scan = r;                           // wave-level inclusive scan
    #pragma unroll
    for (int off = 1; off < 64; off <<= 1) {
        int n = __shfl_up(scan, off, 64);
        if (lane >= off) scan += n;
    }
    if (lane == 63) wave_tot[wave] = scan;
    __syncthreads();                        // lut init + rows + wave_tot visible

    int wpre = 0;
    #pragma unroll
    for (int w = 0; w < 8; ++w) wpre += (w < wave) ? wave_tot[w] : 0;
    int k = wpre + scan - r;                // exclusive prefix = t-start of l's span
    int total = 0;
    #pragma unroll
    for (int w = 0; w < 8; ++w) total += wave_tot[w];

    // ---- scatter: each l writes its own span (disjoint ranges, no race) ----
    for (int q = 0; q < r; ++q, ++k) if (k < T) lut[k] = (unsigned short)tid;

    // ---- side outputs (one block per batch) ----
    if (rp == 0) {
        out[OUT_REP + b * L + tid] = (float)r;
        if (tid == 0) out[OUT_LAT + b] = (float)total;
    }
    __syncthreads();                        // scatter done

    // ---- payload: 64 KB contiguous span = 4 rows x 2 halves of 8 KB,
    //      LUT read once per half, indices shared by all 4 rows ----
    float4* out4 = reinterpret_cast<float4*>(out + ((size_t)b * D + ROWS * rp) * T);

    const uint2 lu0 = *reinterpret_cast<const uint2*>(&lut[4 * tid]);         // h=0
    const uint2 lu1 = *reinterpret_cast<const uint2*>(&lut[2048 + 4 * tid]);  // h=1
    const int la0 = lu0.x & 0xffff, lb0 = lu0.x >> 16;
    const int lc0 = lu0.y & 0xffff, ld0 = lu0.y >> 16;
    const int la1 = lu1.x & 0xffff, lb1 = lu1.x >> 16;
    const int lc1 = lu1.y & 0xffff, ld1 = lu1.y >> 16;
    const bool z1 = (total <= 2048);        // whole h=1 half past latent_length

    #pragma unroll
    for (int rr = 0; rr < ROWS; ++rr) {
        const float* rowp = rows + rr * L;

        // h = 0 (t = 4*tid): always live (total > 0 in practice; masks cover edge)
        float4 v0;
        v0.x = rowp[la0 & 511];             // monotone l across lanes: ~2-way banks
        v0.y = rowp[lb0 & 511];
        v0.z = rowp[lc0 & 511];
        v0.w = rowp[ld0 & 511];
        if (la0 == 0xffff) v0.x = 0.0f;
        if (lb0 == 0xffff) v0.y = 0.0f;
        if (lc0 == 0xffff) v0.z = 0.0f;
        if (ld0 == 0xffff) v0.w = 0.0f;
        out4[rr * 1024 + tid] = v0;         // block-wide 8 KB sequential store

        // h = 1 (t = 2048 + 4*tid)
        float4 v1 = make_float4(0.f, 0.f, 0.f, 0.f);
        if (!z1) {
            v1.x = rowp[la1 & 511];
            v1.y = rowp[lb1 & 511];
            v1.z = rowp[lc1 & 511];
            v1.w = rowp[ld1 & 511];
            if (la1 == 0xffff) v1.x = 0.0f;
            if (lb1 == 0xffff) v1.y = 0.0f;
            if (lc1 == 0xffff) v1.z = 0.0f;
            if (ld1 == 0xffff) v1.w = 0.0f;
        }
        out4[rr * 1024 + 512 + tid] = v1;
    }
}

extern "C" void kernel_launch(void* const* d_in, const int* in_sizes, int n_in,
                              void* d_out, int out_size, void* d_ws, size_t ws_size,
                              hipStream_t stream) {
    const float* enc = (const float*)d_in[0];   // (B, D, L) fp32
    const float* dur = (const float*)d_in[1];   // (B, L)    fp32
    float* out = (float*)d_out;
    encoder_expand_kernel<<<dim3(B * (D / ROWS)), dim3(512), 0, stream>>>(enc, dur, out);
}